// Round 1
// baseline (393.605 us; speedup 1.0000x reference)
//
#include <hip/hip_runtime.h>

// Batched greedy NMS matching the JAX reference:
//   order = stable argsort(-scores); canonical boxes; greedy suppress IoU>0.7;
//   out[b][k] = rois[b][order-of-kth-kept] for k < count, else rois[b][0].
// One block per batch. Early-exit when max_out kept boxes found (the
// reference only emits the first max_out kept rows).

constexpr int   kN       = 2048;
constexpr int   kThreads = 1024;
constexpr float kIouThr  = 0.7f;

__global__ __launch_bounds__(kThreads)
void nms_kernel(const float* __restrict__ rois,    // [B, kN, 4]
                const float* __restrict__ scores,  // [B, kN]
                float* __restrict__ out,           // [B, max_out, 4]
                int max_out)
{
    const int b   = blockIdx.x;
    const int tid = threadIdx.x;

    __shared__ float        s_score[kN];
    __shared__ int          s_order[kN];
    __shared__ float4       s_box[kN];     // canonicalized, score-sorted
    __shared__ float        s_area[kN];
    __shared__ unsigned int s_sup[kN / 32];
    __shared__ int          s_count;

    const float* brois   = rois   + (size_t)b * kN * 4;
    const float* bscores = scores + (size_t)b * kN;

    for (int i = tid; i < kN; i += kThreads) s_score[i] = bscores[i];
    for (int i = tid; i < kN / 32; i += kThreads) s_sup[i] = 0u;
    if (tid == 0) s_count = 0;
    __syncthreads();

    // ---- stable descending rank (== jnp.argsort(-scores)) ----
    for (int i = tid; i < kN; i += kThreads) {
        const float si = s_score[i];
        int rank = 0;
        const float4* s4 = reinterpret_cast<const float4*>(s_score);
        for (int j4 = 0; j4 < kN / 4; ++j4) {
            const float4 v = s4[j4];
            const int j = j4 * 4;
            rank += (v.x > si) || (v.x == si && (j + 0) < i);
            rank += (v.y > si) || (v.y == si && (j + 1) < i);
            rank += (v.z > si) || (v.z == si && (j + 2) < i);
            rank += (v.w > si) || (v.w == si && (j + 3) < i);
        }
        s_order[rank] = i;   // ranks are a permutation: no conflicts
    }
    __syncthreads();

    // ---- gather canonicalized boxes in score order ----
    for (int r = tid; r < kN; r += kThreads) {
        const int idx = s_order[r];
        const float4 bx = *reinterpret_cast<const float4*>(brois + (size_t)idx * 4);
        const float cy1 = fminf(bx.x, bx.z), cy2 = fmaxf(bx.x, bx.z);
        const float cx1 = fminf(bx.y, bx.w), cx2 = fmaxf(bx.y, bx.w);
        s_box[r]  = make_float4(cy1, cx1, cy2, cx2);
        s_area[r] = (cy2 - cy1) * (cx2 - cx1);
    }
    __syncthreads();

    // ---- greedy suppression; early-exit at max_out kept ----
    for (int i = 0; i < kN; ++i) {
        const bool sup_i = (s_sup[i >> 5] >> (i & 31)) & 1u;
        if (!sup_i) {
            const float4 bi = s_box[i];
            const float  ai = s_area[i];
            // j > i only: never touches bit i mid-iteration (race-free),
            // and bits j < i are already decided so they don't matter.
            for (int j = i + 1 + tid; j < kN; j += kThreads) {
                const float4 bj = s_box[j];
                const float iy1 = fmaxf(bi.x, bj.x);
                const float ix1 = fmaxf(bi.y, bj.y);
                const float iy2 = fminf(bi.z, bj.z);
                const float ix2 = fminf(bi.w, bj.w);
                const float inter = fmaxf(iy2 - iy1, 0.0f) * fmaxf(ix2 - ix1, 0.0f);
                const float uni   = ai + s_area[j] - inter;
                const float iou   = (uni > 0.0f) ? (inter / uni) : 0.0f;
                if (iou > kIouThr) atomicOr(&s_sup[j >> 5], 1u << (j & 31));
            }
            if (tid == 0) {
                const int c = s_count;
                if (c < max_out) {
                    const int oidx = s_order[i];
                    reinterpret_cast<float4*>(out)[(size_t)b * max_out + c] =
                        *reinterpret_cast<const float4*>(brois + (size_t)oidx * 4);
                }
                s_count = c + 1;
            }
        }
        __syncthreads();                             // (A) updates visible
        const bool stop = (s_count >= max_out);      // uniform snapshot
        __syncthreads();                             // (B) reads done before next write
        if (stop) break;
    }

    // ---- padding with original boxes[0] (reference pads sel with 0) ----
    const int c = min(s_count, max_out);
    const float4 pad = *reinterpret_cast<const float4*>(brois);
    for (int r = c + tid; r < max_out; r += kThreads) {
        reinterpret_cast<float4*>(out)[(size_t)b * max_out + r] = pad;
    }
}

extern "C" void kernel_launch(void* const* d_in, const int* in_sizes, int n_in,
                              void* d_out, int out_size, void* d_ws, size_t ws_size,
                              hipStream_t stream)
{
    const float* rois   = (const float*)d_in[0];
    const float* scores = (const float*)d_in[1];
    float* out = (float*)d_out;

    const int B       = in_sizes[1] / kN;        // scores are [B, kN]
    const int max_out = out_size / (4 * B);      // out is [B, max_out, 4]

    nms_kernel<<<dim3(B), dim3(kThreads), 0, stream>>>(rois, scores, out, max_out);
}

// Round 2
// 144.927 us; speedup vs baseline: 2.7159x; 2.7159x over previous
//
#include <hip/hip_runtime.h>

// 3-phase bitmask NMS (matches JAX reference greedy semantics exactly):
//  P1 rank_kernel : stable argsort(-scores) via comparison counting ->
//                   order[b][r] (orig idx) + canonicalized sorted boxes in ws
//  P2 mask_kernel : suppression bit-rows mask[b][i][w] = IoU(box_i, box_j)>thr
//                   (one wave per row, ballot; only words w >= i>>6*2 valid)
//  P3 scan_kernel : serial greedy scan, suppression bitmap in registers
//                   (1 dword/lane over one wave), early-exit at max_out kept.
// Falls back to the single-kernel round-1 version if ws is too small.

constexpr int   kN       = 2048;
constexpr float kIouThr  = 0.7f;

// ---------------------------------------------------------------- P1: rank
constexpr int kRankThreads = 256;   // rows per block == threads

__global__ __launch_bounds__(kRankThreads)
void rank_kernel(const float* __restrict__ rois,    // [B, kN, 4]
                 const float* __restrict__ scores,  // [B, kN]
                 int* __restrict__ order,           // [B, kN] ws
                 float4* __restrict__ boxes_sorted) // [B, kN] ws (canonical)
{
    const int b  = blockIdx.y;
    const int r0 = blockIdx.x * kRankThreads;

    __shared__ float s_score[kN];
    const float* bs = scores + (size_t)b * kN;
    for (int t = threadIdx.x; t < kN; t += kRankThreads) s_score[t] = bs[t];
    __syncthreads();

    const int   i  = r0 + threadIdx.x;
    const float si = s_score[i];
    int rank = 0;
    const float4* s4 = reinterpret_cast<const float4*>(s_score);
    for (int j4 = 0; j4 < kN / 4; ++j4) {
        const float4 v = s4[j4];
        const int j = j4 * 4;
        rank += (v.x > si) || (v.x == si && (j + 0) < i);
        rank += (v.y > si) || (v.y == si && (j + 1) < i);
        rank += (v.z > si) || (v.z == si && (j + 2) < i);
        rank += (v.w > si) || (v.w == si && (j + 3) < i);
    }
    order[(size_t)b * kN + rank] = i;

    const float4 bx = reinterpret_cast<const float4*>(rois)[(size_t)b * kN + i];
    const float cy1 = fminf(bx.x, bx.z), cy2 = fmaxf(bx.x, bx.z);
    const float cx1 = fminf(bx.y, bx.w), cx2 = fmaxf(bx.y, bx.w);
    boxes_sorted[(size_t)b * kN + rank] = make_float4(cy1, cx1, cy2, cx2);
}

// ---------------------------------------------------------------- P2: mask
constexpr int kMaskThreads = 1024;          // 16 waves
constexpr int kRowsPerMaskBlock = 32;       // 2 rows per wave

__global__ __launch_bounds__(kMaskThreads)
void mask_kernel(const float4* __restrict__ boxes_sorted, // [B, kN]
                 unsigned int* __restrict__ mask)         // [B, kN, 64]
{
    const int b  = blockIdx.y;
    const int r0 = blockIdx.x * kRowsPerMaskBlock;

    __shared__ float4 s_box[kN];
    __shared__ float  s_area[kN];
    for (int t = threadIdx.x; t < kN; t += kMaskThreads) {
        const float4 c = boxes_sorted[(size_t)b * kN + t];
        s_box[t]  = c;
        s_area[t] = (c.z - c.x) * (c.w - c.y);
    }
    __syncthreads();

    const int wave = threadIdx.x >> 6;
    const int lane = threadIdx.x & 63;

    for (int rr = 0; rr < 2; ++rr) {
        const int i = r0 + wave * 2 + rr;
        const float4 bi = s_box[i];
        const float  ai = s_area[i];
        unsigned int myw = 0u;
        const int k0 = i >> 6;                 // only j-words >= 2*k0 matter
        for (int k = k0; k < kN / 64; ++k) {
            const int j = k * 64 + lane;
            const float4 bj = s_box[j];
            const float iy1 = fmaxf(bi.x, bj.x);
            const float ix1 = fmaxf(bi.y, bj.y);
            const float iy2 = fminf(bi.z, bj.z);
            const float ix2 = fminf(bi.w, bj.w);
            const float inter = fmaxf(iy2 - iy1, 0.0f) * fmaxf(ix2 - ix1, 0.0f);
            const float uni   = ai + s_area[j] - inter;
            const bool  sup   = (uni > 0.0f) && (inter / uni > kIouThr);
            const unsigned long long bal = __ballot(sup);   // bit l <-> j=k*64+l
            if ((lane >> 1) == k)
                myw = (lane & 1) ? (unsigned int)(bal >> 32) : (unsigned int)bal;
        }
        mask[((size_t)b * kN + i) * 64 + lane] = myw;       // coalesced 256B
    }
}

// ---------------------------------------------------------------- P3: scan
__global__ __launch_bounds__(64)
void scan_kernel(const unsigned int* __restrict__ mask,  // [B, kN, 64]
                 const int* __restrict__ order,          // [B, kN]
                 const float* __restrict__ rois,         // [B, kN, 4] orig
                 float* __restrict__ out,                // [B, max_out, 4]
                 int max_out)
{
    const int b    = blockIdx.x;
    const int lane = threadIdx.x;
    const unsigned int* m = mask + (size_t)b * kN * 64;

    __shared__ int s_keep[512];          // kept sorted-positions (max_out<=512)

    unsigned int sup = 0u;               // lane w owns bits [32w, 32w+32)
    int count = 0;

    // 1-deep pipelined 8-row chunks
#define LOAD8(dst0,dst1,dst2,dst3,dst4,dst5,dst6,dst7,BASE)                    \
    dst0 = m[(size_t)((BASE)+0)*64 + lane]; dst1 = m[(size_t)((BASE)+1)*64 + lane]; \
    dst2 = m[(size_t)((BASE)+2)*64 + lane]; dst3 = m[(size_t)((BASE)+3)*64 + lane]; \
    dst4 = m[(size_t)((BASE)+4)*64 + lane]; dst5 = m[(size_t)((BASE)+5)*64 + lane]; \
    dst6 = m[(size_t)((BASE)+6)*64 + lane]; dst7 = m[(size_t)((BASE)+7)*64 + lane];

    unsigned int c0,c1,c2,c3,c4,c5,c6,c7;
    LOAD8(c0,c1,c2,c3,c4,c5,c6,c7,0)

#define STEP(RT, T) {                                                          \
        const int i = base + (T);                                              \
        const unsigned int wsel = __shfl(sup, i >> 5);                         \
        if (count < max_out && !((wsel >> (i & 31)) & 1u)) {                   \
            if (lane == 0) s_keep[count] = i;                                  \
            sup |= (lane >= (i >> 5)) ? (RT) : 0u;                             \
            ++count;                                                           \
        } }

    for (int base = 0; base < kN && count < max_out; base += 8) {
        unsigned int n0,n1,n2,n3,n4,n5,n6,n7;
        if (base + 8 < kN) { LOAD8(n0,n1,n2,n3,n4,n5,n6,n7,base+8) }
        else { n0=n1=n2=n3=n4=n5=n6=n7=0u; }
        STEP(c0,0) STEP(c1,1) STEP(c2,2) STEP(c3,3)
        STEP(c4,4) STEP(c5,5) STEP(c6,6) STEP(c7,7)
        c0=n0; c1=n1; c2=n2; c3=n3; c4=n4; c5=n5; c6=n6; c7=n7;
    }
#undef STEP
#undef LOAD8

    __syncthreads();   // single wave; LDS visibility safety

    const float4* rois4 = reinterpret_cast<const float4*>(rois) + (size_t)b * kN;
    float4*       out4  = reinterpret_cast<float4*>(out) + (size_t)b * max_out;
    const int*    bo    = order + (size_t)b * kN;
    for (int c = lane; c < max_out; c += 64) {
        int oidx = 0;                                   // pad with orig box 0
        if (c < count) oidx = bo[s_keep[c]];
        out4[c] = rois4[oidx];
    }
}

// ------------------------------------------------- fallback (round-1 kernel)
constexpr int kFbThreads = 1024;

__global__ __launch_bounds__(kFbThreads)
void nms_fallback(const float* __restrict__ rois, const float* __restrict__ scores,
                  float* __restrict__ out, int max_out)
{
    const int b   = blockIdx.x;
    const int tid = threadIdx.x;
    __shared__ float        s_score[kN];
    __shared__ int          s_order[kN];
    __shared__ float4       s_box[kN];
    __shared__ float        s_area[kN];
    __shared__ unsigned int s_sup[kN / 32];
    __shared__ int          s_count;
    const float* brois   = rois   + (size_t)b * kN * 4;
    const float* bscores = scores + (size_t)b * kN;
    for (int i = tid; i < kN; i += kFbThreads) s_score[i] = bscores[i];
    for (int i = tid; i < kN / 32; i += kFbThreads) s_sup[i] = 0u;
    if (tid == 0) s_count = 0;
    __syncthreads();
    for (int i = tid; i < kN; i += kFbThreads) {
        const float si = s_score[i];
        int rank = 0;
        const float4* s4 = reinterpret_cast<const float4*>(s_score);
        for (int j4 = 0; j4 < kN / 4; ++j4) {
            const float4 v = s4[j4];
            const int j = j4 * 4;
            rank += (v.x > si) || (v.x == si && (j + 0) < i);
            rank += (v.y > si) || (v.y == si && (j + 1) < i);
            rank += (v.z > si) || (v.z == si && (j + 2) < i);
            rank += (v.w > si) || (v.w == si && (j + 3) < i);
        }
        s_order[rank] = i;
    }
    __syncthreads();
    for (int r = tid; r < kN; r += kFbThreads) {
        const int idx = s_order[r];
        const float4 bx = *reinterpret_cast<const float4*>(brois + (size_t)idx * 4);
        const float cy1 = fminf(bx.x, bx.z), cy2 = fmaxf(bx.x, bx.z);
        const float cx1 = fminf(bx.y, bx.w), cx2 = fmaxf(bx.y, bx.w);
        s_box[r]  = make_float4(cy1, cx1, cy2, cx2);
        s_area[r] = (cy2 - cy1) * (cx2 - cx1);
    }
    __syncthreads();
    for (int i = 0; i < kN; ++i) {
        const bool sup_i = (s_sup[i >> 5] >> (i & 31)) & 1u;
        if (!sup_i) {
            const float4 bi = s_box[i];
            const float  ai = s_area[i];
            for (int j = i + 1 + tid; j < kN; j += kFbThreads) {
                const float4 bj = s_box[j];
                const float iy1 = fmaxf(bi.x, bj.x);
                const float ix1 = fmaxf(bi.y, bj.y);
                const float iy2 = fminf(bi.z, bj.z);
                const float ix2 = fminf(bi.w, bj.w);
                const float inter = fmaxf(iy2 - iy1, 0.0f) * fmaxf(ix2 - ix1, 0.0f);
                const float uni   = ai + s_area[j] - inter;
                const float iou   = (uni > 0.0f) ? (inter / uni) : 0.0f;
                if (iou > kIouThr) atomicOr(&s_sup[j >> 5], 1u << (j & 31));
            }
            if (tid == 0) {
                const int c = s_count;
                if (c < max_out) {
                    const int oidx = s_order[i];
                    reinterpret_cast<float4*>(out)[(size_t)b * max_out + c] =
                        *reinterpret_cast<const float4*>(brois + (size_t)oidx * 4);
                }
                s_count = c + 1;
            }
        }
        __syncthreads();
        const bool stop = (s_count >= max_out);
        __syncthreads();
        if (stop) break;
    }
    const int c = min(s_count, max_out);
    const float4 pad = *reinterpret_cast<const float4*>(brois);
    for (int r = c + tid; r < max_out; r += kFbThreads) {
        reinterpret_cast<float4*>(out)[(size_t)b * max_out + r] = pad;
    }
}

// ---------------------------------------------------------------- launch
extern "C" void kernel_launch(void* const* d_in, const int* in_sizes, int n_in,
                              void* d_out, int out_size, void* d_ws, size_t ws_size,
                              hipStream_t stream)
{
    const float* rois   = (const float*)d_in[0];
    const float* scores = (const float*)d_in[1];
    float* out = (float*)d_out;

    const int B       = in_sizes[1] / kN;        // scores are [B, kN]
    const int max_out = out_size / (4 * B);      // out is [B, max_out, 4]

    const size_t maskBytes  = (size_t)B * kN * 64 * sizeof(unsigned int); // 8 MB
    const size_t orderBytes = (size_t)B * kN * sizeof(int);
    const size_t boxesBytes = (size_t)B * kN * sizeof(float4);

    if (ws_size >= maskBytes + orderBytes + boxesBytes && max_out <= 512) {
        unsigned int* mask  = (unsigned int*)d_ws;
        int*          order = (int*)((char*)d_ws + maskBytes);
        float4*       boxes = (float4*)((char*)d_ws + maskBytes + orderBytes);

        rank_kernel<<<dim3(kN / kRankThreads, B), dim3(kRankThreads), 0, stream>>>(
            rois, scores, order, boxes);
        mask_kernel<<<dim3(kN / kRowsPerMaskBlock, B), dim3(kMaskThreads), 0, stream>>>(
            boxes, mask);
        scan_kernel<<<dim3(B), dim3(64), 0, stream>>>(mask, order, rois, out, max_out);
    } else {
        nms_fallback<<<dim3(B), dim3(kFbThreads), 0, stream>>>(rois, scores, out, max_out);
    }
}

// Round 3
// 79.820 us; speedup vs baseline: 4.9312x; 1.8157x over previous
//
#include <hip/hip_runtime.h>

// 3-phase windowed-bitmask NMS (bit-exact vs the JAX reference):
//  P1 rank_kernel : stable argsort(-scores) via comparison counting (2 threads
//                   per row, halves combined by shfl) -> order + canonical
//                   score-sorted boxes in ws.
//  P2 mask_kernel : suppression bit-rows ONLY for the top kM x kM window
//                   (scan early-exits at ~310 << kM for this workload).
//  P3 scan_kernel : serial greedy scan over the window, suppression bitmap in
//                   registers (1 dword/lane), early-exit at max_out kept.
//                   If the window is exhausted (adversarial data), continues
//                   with exact lazy IoU vs the kept list (same IEEE ops).
// Falls back to a single-kernel version if ws is too small.

constexpr int   kN      = 2048;
constexpr int   kM      = 640;     // mask window (rows & cols)
constexpr float kIouThr = 0.7f;

// ---------------------------------------------------------------- P1: rank
constexpr int kRankThreads = 256;          // 128 rows/block, 2 threads/row

__global__ __launch_bounds__(kRankThreads)
void rank_kernel(const float* __restrict__ rois,    // [B, kN, 4]
                 const float* __restrict__ scores,  // [B, kN]
                 int* __restrict__ order,           // [B, kN] ws
                 float4* __restrict__ boxes_sorted) // [B, kN] ws (canonical)
{
    const int b  = blockIdx.y;
    const int r0 = blockIdx.x * (kRankThreads / 2);

    __shared__ float s_score[kN];
    const float* bs = scores + (size_t)b * kN;
    for (int t = threadIdx.x; t < kN; t += kRankThreads) s_score[t] = bs[t];
    __syncthreads();

    const int   row  = r0 + (threadIdx.x >> 1);
    const int   half = threadIdx.x & 1;
    const float si   = s_score[row];

    int rank = 0;
    const float4* s4 = reinterpret_cast<const float4*>(s_score);
    const int j4b = half * (kN / 8), j4e = j4b + kN / 8;
    for (int j4 = j4b; j4 < j4e; ++j4) {
        const float4 v = s4[j4];
        const int j = j4 * 4;
        rank += (v.x > si) || (v.x == si && (j + 0) < row);
        rank += (v.y > si) || (v.y == si && (j + 1) < row);
        rank += (v.z > si) || (v.z == si && (j + 2) < row);
        rank += (v.w > si) || (v.w == si && (j + 3) < row);
    }
    const int total = rank + __shfl_xor(rank, 1);

    if (half == 0) {
        order[(size_t)b * kN + total] = row;
        const float4 bx = reinterpret_cast<const float4*>(rois)[(size_t)b * kN + row];
        const float cy1 = fminf(bx.x, bx.z), cy2 = fmaxf(bx.x, bx.z);
        const float cx1 = fminf(bx.y, bx.w), cx2 = fmaxf(bx.y, bx.w);
        boxes_sorted[(size_t)b * kN + total] = make_float4(cy1, cx1, cy2, cx2);
    }
}

// ---------------------------------------------------------------- P2: mask
constexpr int kMaskThreads = 1024;          // 16 waves
constexpr int kRowsPerMaskBlock = 32;       // 2 rows per wave

__global__ __launch_bounds__(kMaskThreads)
void mask_kernel(const float4* __restrict__ boxes_sorted, // [B, kN]
                 unsigned int* __restrict__ mask)         // [B, kM, 64]
{
    const int b  = blockIdx.y;
    const int r0 = blockIdx.x * kRowsPerMaskBlock;

    __shared__ float4 s_box[kM];
    __shared__ float  s_area[kM];
    for (int t = threadIdx.x; t < kM; t += kMaskThreads) {
        const float4 c = boxes_sorted[(size_t)b * kN + t];
        s_box[t]  = c;
        s_area[t] = (c.z - c.x) * (c.w - c.y);
    }
    __syncthreads();

    const int wave = threadIdx.x >> 6;
    const int lane = threadIdx.x & 63;

    for (int rr = 0; rr < 2; ++rr) {
        const int i = r0 + wave * 2 + rr;          // i < kM
        const float4 bi = s_box[i];
        const float  ai = s_area[i];
        unsigned int myw = 0u;
        const int k0 = i >> 6;
        for (int k = k0; k < kM / 64; ++k) {
            const int j = k * 64 + lane;
            const float4 bj = s_box[j];
            const float iy1 = fmaxf(bi.x, bj.x);
            const float ix1 = fmaxf(bi.y, bj.y);
            const float iy2 = fminf(bi.z, bj.z);
            const float ix2 = fminf(bi.w, bj.w);
            const float inter = fmaxf(iy2 - iy1, 0.0f) * fmaxf(ix2 - ix1, 0.0f);
            const float uni   = ai + s_area[j] - inter;
            const bool  sup   = (uni > 0.0f) && (inter / uni > kIouThr);
            const unsigned long long bal = __ballot(sup);   // bit l <-> j=k*64+l
            if ((lane >> 1) == k)
                myw = (lane & 1) ? (unsigned int)(bal >> 32) : (unsigned int)bal;
        }
        mask[((size_t)b * kM + i) * 64 + lane] = myw;       // lanes >= kM/32 -> 0
    }
}

// ---------------------------------------------------------------- P3: scan
__global__ __launch_bounds__(64)
void scan_kernel(const unsigned int* __restrict__ mask,    // [B, kM, 64]
                 const int* __restrict__ order,            // [B, kN]
                 const float4* __restrict__ boxes_sorted,  // [B, kN] canonical
                 const float* __restrict__ rois,           // [B, kN, 4] orig
                 float* __restrict__ out,                  // [B, max_out, 4]
                 int max_out)
{
    const int b    = blockIdx.x;
    const int lane = threadIdx.x;
    const unsigned int* m = mask + (size_t)b * kM * 64;

    __shared__ int    s_keep[512];      // kept sorted-positions (max_out<=512)
    __shared__ float4 s_kbox[512];      // kept canonical boxes (fallback only)
    __shared__ float  s_karea[512];

    unsigned int sup = 0u;              // lane w owns bits [32w, 32w+32)
    int count = 0;

#define LOAD8(dst0,dst1,dst2,dst3,dst4,dst5,dst6,dst7,BASE)                    \
    dst0 = m[(size_t)((BASE)+0)*64 + lane]; dst1 = m[(size_t)((BASE)+1)*64 + lane]; \
    dst2 = m[(size_t)((BASE)+2)*64 + lane]; dst3 = m[(size_t)((BASE)+3)*64 + lane]; \
    dst4 = m[(size_t)((BASE)+4)*64 + lane]; dst5 = m[(size_t)((BASE)+5)*64 + lane]; \
    dst6 = m[(size_t)((BASE)+6)*64 + lane]; dst7 = m[(size_t)((BASE)+7)*64 + lane];

    unsigned int c0,c1,c2,c3,c4,c5,c6,c7;
    LOAD8(c0,c1,c2,c3,c4,c5,c6,c7,0)

#define STEP(RT, T) {                                                          \
        const int i = base + (T);                                              \
        const unsigned int wsel = __shfl(sup, i >> 5);                         \
        if (count < max_out && !((wsel >> (i & 31)) & 1u)) {                   \
            if (lane == 0) s_keep[count] = i;                                  \
            sup |= (lane >= (i >> 5)) ? (RT) : 0u;                             \
            ++count;                                                           \
        } }

    for (int base = 0; base < kM && count < max_out; base += 8) {
        unsigned int n0,n1,n2,n3,n4,n5,n6,n7;
        if (base + 8 < kM) { LOAD8(n0,n1,n2,n3,n4,n5,n6,n7,base+8) }
        else { n0=n1=n2=n3=n4=n5=n6=n7=0u; }
        STEP(c0,0) STEP(c1,1) STEP(c2,2) STEP(c3,3)
        STEP(c4,4) STEP(c5,5) STEP(c6,6) STEP(c7,7)
        c0=n0; c1=n1; c2=n2; c3=n3; c4=n4; c5=n5; c6=n6; c7=n7;
    }
#undef STEP
#undef LOAD8

    // ---- lazy continuation past the window (correctness insurance) ----
    if (count < max_out) {
        __syncthreads();
        const float4* bsrt = boxes_sorted + (size_t)b * kN;
        for (int k = lane; k < count; k += 64) {
            const float4 c = bsrt[s_keep[k]];
            s_kbox[k]  = c;
            s_karea[k] = (c.z - c.x) * (c.w - c.y);
        }
        __syncthreads();
        for (int i = kM; i < kN && count < max_out; ++i) {
            const float4 bi = bsrt[i];
            const float  ai = (bi.z - bi.x) * (bi.w - bi.y);
            bool supb = false;
            for (int k = lane; k < count; k += 64) {
                const float4 bk = s_kbox[k];
                const float iy1 = fmaxf(bi.x, bk.x);
                const float ix1 = fmaxf(bi.y, bk.y);
                const float iy2 = fminf(bi.z, bk.z);
                const float ix2 = fminf(bi.w, bk.w);
                const float inter = fmaxf(iy2 - iy1, 0.0f) * fmaxf(ix2 - ix1, 0.0f);
                const float uni   = s_karea[k] + ai - inter;   // area[i]+area[k] order:
                // reference: area[kept] + area[i] ordering is area[:,None]+area[None,:]
                // addition is commutative in f32 -> same value either way
                supb = supb || ((uni > 0.0f) && (inter / uni > kIouThr));
            }
            if (!__any(supb)) {
                if (lane == 0) {
                    s_keep[count]  = i;
                    s_kbox[count]  = bi;
                    s_karea[count] = ai;
                }
                ++count;
            }
        }
    }

    __syncthreads();

    const float4* rois4 = reinterpret_cast<const float4*>(rois) + (size_t)b * kN;
    float4*       out4  = reinterpret_cast<float4*>(out) + (size_t)b * max_out;
    const int*    bo    = order + (size_t)b * kN;
    for (int c = lane; c < max_out; c += 64) {
        int oidx = 0;                                   // pad with orig box 0
        if (c < count) oidx = bo[s_keep[c]];
        out4[c] = rois4[oidx];
    }
}

// ------------------------------------------------- fallback (round-1 kernel)
constexpr int kFbThreads = 1024;

__global__ __launch_bounds__(kFbThreads)
void nms_fallback(const float* __restrict__ rois, const float* __restrict__ scores,
                  float* __restrict__ out, int max_out)
{
    const int b   = blockIdx.x;
    const int tid = threadIdx.x;
    __shared__ float        s_score[kN];
    __shared__ int          s_order[kN];
    __shared__ float4       s_box[kN];
    __shared__ float        s_area[kN];
    __shared__ unsigned int s_sup[kN / 32];
    __shared__ int          s_count;
    const float* brois   = rois   + (size_t)b * kN * 4;
    const float* bscores = scores + (size_t)b * kN;
    for (int i = tid; i < kN; i += kFbThreads) s_score[i] = bscores[i];
    for (int i = tid; i < kN / 32; i += kFbThreads) s_sup[i] = 0u;
    if (tid == 0) s_count = 0;
    __syncthreads();
    for (int i = tid; i < kN; i += kFbThreads) {
        const float si = s_score[i];
        int rank = 0;
        const float4* s4 = reinterpret_cast<const float4*>(s_score);
        for (int j4 = 0; j4 < kN / 4; ++j4) {
            const float4 v = s4[j4];
            const int j = j4 * 4;
            rank += (v.x > si) || (v.x == si && (j + 0) < i);
            rank += (v.y > si) || (v.y == si && (j + 1) < i);
            rank += (v.z > si) || (v.z == si && (j + 2) < i);
            rank += (v.w > si) || (v.w == si && (j + 3) < i);
        }
        s_order[rank] = i;
    }
    __syncthreads();
    for (int r = tid; r < kN; r += kFbThreads) {
        const int idx = s_order[r];
        const float4 bx = *reinterpret_cast<const float4*>(brois + (size_t)idx * 4);
        const float cy1 = fminf(bx.x, bx.z), cy2 = fmaxf(bx.x, bx.z);
        const float cx1 = fminf(bx.y, bx.w), cx2 = fmaxf(bx.y, bx.w);
        s_box[r]  = make_float4(cy1, cx1, cy2, cx2);
        s_area[r] = (cy2 - cy1) * (cx2 - cx1);
    }
    __syncthreads();
    for (int i = 0; i < kN; ++i) {
        const bool sup_i = (s_sup[i >> 5] >> (i & 31)) & 1u;
        if (!sup_i) {
            const float4 bi = s_box[i];
            const float  ai = s_area[i];
            for (int j = i + 1 + tid; j < kN; j += kFbThreads) {
                const float4 bj = s_box[j];
                const float iy1 = fmaxf(bi.x, bj.x);
                const float ix1 = fmaxf(bi.y, bj.y);
                const float iy2 = fminf(bi.z, bj.z);
                const float ix2 = fminf(bi.w, bj.w);
                const float inter = fmaxf(iy2 - iy1, 0.0f) * fmaxf(ix2 - ix1, 0.0f);
                const float uni   = ai + s_area[j] - inter;
                const float iou   = (uni > 0.0f) ? (inter / uni) : 0.0f;
                if (iou > kIouThr) atomicOr(&s_sup[j >> 5], 1u << (j & 31));
            }
            if (tid == 0) {
                const int c = s_count;
                if (c < max_out) {
                    const int oidx = s_order[i];
                    reinterpret_cast<float4*>(out)[(size_t)b * max_out + c] =
                        *reinterpret_cast<const float4*>(brois + (size_t)oidx * 4);
                }
                s_count = c + 1;
            }
        }
        __syncthreads();
        const bool stop = (s_count >= max_out);
        __syncthreads();
        if (stop) break;
    }
    const int c = min(s_count, max_out);
    const float4 pad = *reinterpret_cast<const float4*>(brois);
    for (int r = c + tid; r < max_out; r += kFbThreads) {
        reinterpret_cast<float4*>(out)[(size_t)b * max_out + r] = pad;
    }
}

// ---------------------------------------------------------------- launch
extern "C" void kernel_launch(void* const* d_in, const int* in_sizes, int n_in,
                              void* d_out, int out_size, void* d_ws, size_t ws_size,
                              hipStream_t stream)
{
    const float* rois   = (const float*)d_in[0];
    const float* scores = (const float*)d_in[1];
    float* out = (float*)d_out;

    const int B       = in_sizes[1] / kN;        // scores are [B, kN]
    const int max_out = out_size / (4 * B);      // out is [B, max_out, 4]

    const size_t maskBytes  = (size_t)B * kM * 64 * sizeof(unsigned int);
    const size_t orderBytes = (size_t)B * kN * sizeof(int);
    const size_t boxesBytes = (size_t)B * kN * sizeof(float4);

    if (ws_size >= maskBytes + orderBytes + boxesBytes && max_out <= 512) {
        unsigned int* mask  = (unsigned int*)d_ws;
        int*          order = (int*)((char*)d_ws + maskBytes);
        float4*       boxes = (float4*)((char*)d_ws + maskBytes + orderBytes);

        rank_kernel<<<dim3(kN / (kRankThreads / 2), B), dim3(kRankThreads), 0, stream>>>(
            rois, scores, order, boxes);
        mask_kernel<<<dim3(kM / kRowsPerMaskBlock, B), dim3(kMaskThreads), 0, stream>>>(
            boxes, mask);
        scan_kernel<<<dim3(B), dim3(64), 0, stream>>>(mask, order, boxes, rois, out, max_out);
    } else {
        nms_fallback<<<dim3(B), dim3(kFbThreads), 0, stream>>>(rois, scores, out, max_out);
    }
}